// Round 4
// baseline (87.710 us; speedup 1.0000x reference)
//
#include <hip/hip_runtime.h>

// GIB layer: B=2, N=65536, M=8192, K=32; 16 each of cy/cone/disk/ellip gibs;
// out = mean_k(gib_vals) @ lambdas  -> (B, M, 16). fp32 in / fp32 out.
//
// R3 post-mortem: acc[64] spilled (VGPR_Count=60 < 64 accs) -> scratch-latency
// bound at 22% VALUBusy. Fix: 4 type-passes with only 16 live accumulators
// each; reduce + lambda-matvec per pass. Same FLOPs, no spill.
//
// Mapping: 256 thr/block = 32 queries x 8 lanes; each lane handles 4 k's.

#define EPSF 1e-8f
#define LOG2E 1.4426950408889634f

constexpr int Mq  = 8192;
constexpr int Kc  = 32;
constexpr int QPB = 32;   // queries per block
constexpr int KPT = 4;    // k per thread

__global__ __launch_bounds__(256) void gib_kernel(
    const float* __restrict__ points,   // (B, 65536, 3)
    const float* __restrict__ qc,       // (B, 8192, 3)
    const int*   __restrict__ sidx,     // (B, 8192, 32)
    const float* __restrict__ cyp,      // (16,2)
    const float* __restrict__ conep,    // (16,2)
    const float* __restrict__ diskp,    // (16,2)
    const float* __restrict__ ellp,     // (16,3)
    const float* __restrict__ lam,      // (64,16)
    float*       __restrict__ out)      // (B, 8192, 16)
{
    __shared__ float2 cyK[16];          // (c0^2, log2e/(2c1^2+eps))
    __shared__ float2 coK[16];          // (k0, log2e/(2k1^2+eps))
    __shared__ float2 dkK[16];          // (log2e/(d0^2+eps), log2e/(d1^2+eps))
    __shared__ float4 elK[16];          // (log2e/(e*^2+eps) x3, -)
    __shared__ float  lamS[64 * 16];    // lambdas * (1/K)

    const int tid = threadIdx.x;

    if (tid < 16) {
        float c0 = cyp[2 * tid], c1 = cyp[2 * tid + 1];
        cyK[tid] = make_float2(c0 * c0, LOG2E / (2.f * c1 * c1 + EPSF));
        float k0 = conep[2 * tid], k1 = conep[2 * tid + 1];
        coK[tid] = make_float2(k0, LOG2E / (2.f * k1 * k1 + EPSF));
        float d0 = diskp[2 * tid], d1 = diskp[2 * tid + 1];
        dkK[tid] = make_float2(LOG2E / (d0 * d0 + EPSF), LOG2E / (d1 * d1 + EPSF));
        float e0 = ellp[3 * tid], e1 = ellp[3 * tid + 1], e2 = ellp[3 * tid + 2];
        elK[tid] = make_float4(LOG2E / (e0 * e0 + EPSF), LOG2E / (e1 * e1 + EPSF),
                               LOG2E / (e2 * e2 + EPSF), 0.f);
    }
#pragma unroll
    for (int i = 0; i < 4; i++)
        lamS[tid * 4 + i] = lam[tid * 4 + i] * (1.0f / 32.0f);  // fold mean 1/K
    __syncthreads();

    const int q   = blockIdx.x * QPB + (tid >> 3);  // global query id in [0, B*M)
    const int sub = tid & 7;                        // lane-in-query
    const int b   = q >> 13;                        // q / 8192

    const float* qcp = qc + q * 3;
    const float qx = qcp[0], qy = qcp[1], qz = qcp[2];

    const float* ptbase = points + (size_t)b * (65536 * 3);

    // 4 contiguous indices per lane: one coalesced int4 covers the query's 32 idxs
    const int4 idx4 = ((const int4*)(sidx + q * Kc))[sub];
    const int idxs[KPT] = {idx4.x, idx4.y, idx4.z, idx4.w};

    float r2a[KPT], sa[KPT], rza[KPT], rx2a[KPT], ry2a[KPT], rz2a[KPT];
#pragma unroll
    for (int j = 0; j < KPT; j++) {
        const float* pp = ptbase + idxs[j] * 3;
        float rx = pp[0] - qx;
        float ry = pp[1] - qy;
        float rz = pp[2] - qz;
        float rx2 = rx * rx, ry2 = ry * ry, rz2 = rz * rz;
        float r2 = rx2 + ry2;
        r2a[j] = r2;
        sa[j]  = sqrtf(r2 + EPSF);
        rza[j] = rz;
        rx2a[j] = rx2; ry2a[j] = ry2; rz2a[j] = rz2;
    }

    const int o = sub * 2;   // this lane's 2 observer outputs
    float s0 = 0.f, s1 = 0.f;

    // ---- pass 1: cylinders (lambda rows 0..15) ----
    {
        float a[16];
#pragma unroll
        for (int g = 0; g < 16; g++) {
            const float2 p = cyK[g];
            float s = 0.f;
#pragma unroll
            for (int j = 0; j < KPT; j++) {
                float t = r2a[j] - p.x;
                s += exp2f(-(t * t) * p.y);
            }
            a[g] = s;
        }
#pragma unroll
        for (int m = 1; m < 8; m <<= 1)
#pragma unroll
            for (int g = 0; g < 16; g++) a[g] += __shfl_xor(a[g], m, 64);
#pragma unroll
        for (int g = 0; g < 16; g++) {
            const float2 l = *(const float2*)&lamS[g * 16 + o];
            s0 = fmaf(a[g], l.x, s0);
            s1 = fmaf(a[g], l.y, s1);
        }
    }

    // ---- pass 2: cones (lambda rows 16..31) ----
    {
        float a[16];
#pragma unroll
        for (int g = 0; g < 16; g++) {
            const float2 p = coK[g];
            float s = 0.f;
#pragma unroll
            for (int j = 0; j < KPT; j++) {
                float u = fmaf(-p.x, rza[j], sa[j]);
                s += exp2f(-(u * u) * p.y);
            }
            a[g] = s;
        }
#pragma unroll
        for (int m = 1; m < 8; m <<= 1)
#pragma unroll
            for (int g = 0; g < 16; g++) a[g] += __shfl_xor(a[g], m, 64);
#pragma unroll
        for (int g = 0; g < 16; g++) {
            const float2 l = *(const float2*)&lamS[(16 + g) * 16 + o];
            s0 = fmaf(a[g], l.x, s0);
            s1 = fmaf(a[g], l.y, s1);
        }
    }

    // ---- pass 3: disks (lambda rows 32..47) ----
    {
        float a[16];
#pragma unroll
        for (int g = 0; g < 16; g++) {
            const float2 p = dkK[g];
            float s = 0.f;
#pragma unroll
            for (int j = 0; j < KPT; j++)
                s += exp2f(-fmaf(r2a[j], p.x, rz2a[j] * p.y));
            a[g] = s;
        }
#pragma unroll
        for (int m = 1; m < 8; m <<= 1)
#pragma unroll
            for (int g = 0; g < 16; g++) a[g] += __shfl_xor(a[g], m, 64);
#pragma unroll
        for (int g = 0; g < 16; g++) {
            const float2 l = *(const float2*)&lamS[(32 + g) * 16 + o];
            s0 = fmaf(a[g], l.x, s0);
            s1 = fmaf(a[g], l.y, s1);
        }
    }

    // ---- pass 4: ellipsoids (lambda rows 48..63) ----
    {
        float a[16];
#pragma unroll
        for (int g = 0; g < 16; g++) {
            const float4 p = elK[g];
            float s = 0.f;
#pragma unroll
            for (int j = 0; j < KPT; j++)
                s += exp2f(-fmaf(rx2a[j], p.x, fmaf(ry2a[j], p.y, rz2a[j] * p.z)));
            a[g] = s;
        }
#pragma unroll
        for (int m = 1; m < 8; m <<= 1)
#pragma unroll
            for (int g = 0; g < 16; g++) a[g] += __shfl_xor(a[g], m, 64);
#pragma unroll
        for (int g = 0; g < 16; g++) {
            const float2 l = *(const float2*)&lamS[(48 + g) * 16 + o];
            s0 = fmaf(a[g], l.x, s0);
            s1 = fmaf(a[g], l.y, s1);
        }
    }

    float2 w;
    w.x = s0;
    w.y = s1;
    *(float2*)(out + q * 16 + o) = w;
}

extern "C" void kernel_launch(void* const* d_in, const int* in_sizes, int n_in,
                              void* d_out, int out_size, void* d_ws, size_t ws_size,
                              hipStream_t stream) {
    const float* points = (const float*)d_in[0];
    const float* qc     = (const float*)d_in[1];
    const int*   sidx   = (const int*)d_in[2];
    // d_in[3] = mc_points: unused by the reference
    const float* cyp    = (const float*)d_in[4];
    const float* conep  = (const float*)d_in[5];
    const float* diskp  = (const float*)d_in[6];
    const float* ellp   = (const float*)d_in[7];
    const float* lam    = (const float*)d_in[8];
    float*       out    = (float*)d_out;

    const int totalQ = 2 * Mq;              // B*M = 16384
    dim3 grid(totalQ / QPB), block(256);    // 512 blocks
    hipLaunchKernelGGL(gib_kernel, grid, block, 0, stream,
                       points, qc, sidx, cyp, conep, diskp, ellp, lam, out);
}

// Round 5
// 87.018 us; speedup vs baseline: 1.0079x; 1.0079x over previous
//
#include <hip/hip_runtime.h>

// GIB layer: B=2, N=65536, M=8192, K=32; 16 each of cy/cone/disk/ellip gibs;
// out = mean_k(gib_vals) @ lambdas -> (B, M, 16). fp32 in / fp32 out.
//
// R3/R4 post-mortem: 42us with VALUBusy 22%, all pipes idle -> latency-bound
// at 2 waves/SIMD (131072 threads). Restructure: thread = (query, gib-column).
// 16 lanes/query, each lane owns 4 gibs (one per type) over all K=32:
//   - 262144 threads = 16 waves/CU (4 blocks/CU) -> 2x TLP
//   - K-reduction is in-thread (no shuffles); only s[16] butterfly remains:
//     15 shuffles/thread (vs 192), recursive halving w/ bit-reversed lambda slots
//   - geometry staged in LDS once per (q,k): padded q-stride 264 floats so the
//     4 query-groups of a wave hit disjoint banks; reads are 16-lane broadcasts

#define EPSF 1e-8f
#define LOG2E 1.4426950408889634f

constexpr int QPB         = 16;   // queries per block
constexpr int GEO_QSTRIDE = 264;  // 32 k * 8 floats + 8 pad (banks shift 8/query)
constexpr int LAM_STRIDE  = 20;   // 16 + 4 pad (2-way max conflict on b128 rows)

__global__ __launch_bounds__(256, 4) void gib_kernel(
    const float* __restrict__ points,   // (B, 65536, 3)
    const float* __restrict__ qc,       // (B, 8192, 3)
    const int*   __restrict__ sidx,     // (B, 8192, 32)
    const float* __restrict__ cyp,      // (16,2)
    const float* __restrict__ conep,    // (16,2)
    const float* __restrict__ diskp,    // (16,2)
    const float* __restrict__ ellp,     // (16,3)
    const float* __restrict__ lam,      // (64,16)
    float*       __restrict__ out)      // (B, 8192, 16)
{
    __shared__ float  geo[QPB * GEO_QSTRIDE];   // 16.9 KB
    __shared__ float  lamS[64 * LAM_STRIDE];    // 5.1 KB, scaled by 1/K
    __shared__ float4 pkA[16];                  // cyA, cyBn, coK, coBn
    __shared__ float4 pkB[16];                  // dAn, dBn, eAn, eBn
    __shared__ float  pkC[16];                  // eCn

    const int tid = threadIdx.x;

    // ---- stage params (negated, log2e-folded) ----
    if (tid < 16) {
        float c0 = cyp[2 * tid], c1 = cyp[2 * tid + 1];
        float k0 = conep[2 * tid], k1 = conep[2 * tid + 1];
        float d0 = diskp[2 * tid], d1 = diskp[2 * tid + 1];
        float e0 = ellp[3 * tid], e1 = ellp[3 * tid + 1], e2 = ellp[3 * tid + 2];
        pkA[tid] = make_float4(c0 * c0, -LOG2E / (2.f * c1 * c1 + EPSF),
                               k0,      -LOG2E / (2.f * k1 * k1 + EPSF));
        pkB[tid] = make_float4(-LOG2E / (d0 * d0 + EPSF), -LOG2E / (d1 * d1 + EPSF),
                               -LOG2E / (e0 * e0 + EPSF), -LOG2E / (e1 * e1 + EPSF));
        pkC[tid] = -LOG2E / (e2 * e2 + EPSF);
    }

    // ---- stage lambda (64 x 16 -> stride-20 rows, scaled 1/32) ----
    {
        int g = tid >> 2, c = (tid & 3) * 4;
#pragma unroll
        for (int j = 0; j < 4; j++)
            lamS[g * LAM_STRIDE + c + j] = lam[g * 16 + c + j] * (1.0f / 32.0f);
    }

    // ---- phase 1: gather + geometry into LDS (512 items, 2/thread) ----
#pragma unroll
    for (int it = 0; it < 2; it++) {
        int i  = tid + it * 256;
        int ql = i >> 5, k = i & 31;
        int qg = blockIdx.x * QPB + ql;
        int b  = qg >> 13;
        int idx = sidx[qg * 32 + k];
        const float* pp = points + ((size_t)(b << 16) + idx) * 3;
        const float* qq = qc + qg * 3;
        float rx = pp[0] - qq[0];
        float ry = pp[1] - qq[1];
        float rz = pp[2] - qq[2];
        float rx2 = rx * rx, ry2 = ry * ry, rz2 = rz * rz;
        float r2 = rx2 + ry2;
        float s  = sqrtf(r2 + EPSF);
        float* gp = &geo[ql * GEO_QSTRIDE + k * 8];
        *(float4*)gp       = make_float4(r2, s, rz, rx2);
        *(float4*)(gp + 4) = make_float4(ry2, rz2, 0.f, 0.f);
    }
    __syncthreads();

    // ---- phase 2: lane = (query-of-4-in-wave, gib column lg) ----
    const int l  = tid & 63;
    const int ql = (tid >> 6) * 4 + (l >> 4);
    const int lg = l & 15;

    const float4 pA = pkA[lg];
    const float4 pB = pkB[lg];
    const float  eC = pkC[lg];

    float a0 = 0.f, a1 = 0.f, a2 = 0.f, a3 = 0.f;
    const float* gq = &geo[ql * GEO_QSTRIDE];
#pragma unroll 8
    for (int k = 0; k < 32; k++) {
        float4 ga = *(const float4*)(gq + k * 8);
        float2 gb = *(const float2*)(gq + k * 8 + 4);
        float r2 = ga.x, s = ga.y, rz = ga.z, rx2 = ga.w;
        float ry2 = gb.x, rz2 = gb.y;
        float t = r2 - pA.x;
        a0 += exp2f(t * t * pA.y);
        float u = fmaf(-pA.z, rz, s);
        a1 += exp2f(u * u * pA.w);
        a2 += exp2f(fmaf(r2, pB.x, rz2 * pB.y));
        a3 += exp2f(fmaf(rx2, pB.z, fmaf(ry2, pB.w, rz2 * eC)));
    }

    // ---- lambda matvec into bit-reversed slots (slot brev(o) holds observer o)
    float sv[16];
#pragma unroll
    for (int i = 0; i < 16; i++) sv[i] = 0.f;
    const float accs[4] = {a0, a1, a2, a3};
#pragma unroll
    for (int t = 0; t < 4; t++) {
        const float* lrow = &lamS[(t * 16 + lg) * LAM_STRIDE];
        float4 L0 = *(const float4*)(lrow);
        float4 L1 = *(const float4*)(lrow + 4);
        float4 L2 = *(const float4*)(lrow + 8);
        float4 L3 = *(const float4*)(lrow + 12);
        float a = accs[t];
        sv[0]  = fmaf(a, L0.x, sv[0]);   // o=0
        sv[8]  = fmaf(a, L0.y, sv[8]);   // o=1
        sv[4]  = fmaf(a, L0.z, sv[4]);   // o=2
        sv[12] = fmaf(a, L0.w, sv[12]);  // o=3
        sv[2]  = fmaf(a, L1.x, sv[2]);   // o=4
        sv[10] = fmaf(a, L1.y, sv[10]);  // o=5
        sv[6]  = fmaf(a, L1.z, sv[6]);   // o=6
        sv[14] = fmaf(a, L1.w, sv[14]);  // o=7
        sv[1]  = fmaf(a, L2.x, sv[1]);   // o=8
        sv[9]  = fmaf(a, L2.y, sv[9]);   // o=9
        sv[5]  = fmaf(a, L2.z, sv[5]);   // o=10
        sv[13] = fmaf(a, L2.w, sv[13]);  // o=11
        sv[3]  = fmaf(a, L3.x, sv[3]);   // o=12
        sv[11] = fmaf(a, L3.y, sv[11]);  // o=13
        sv[7]  = fmaf(a, L3.z, sv[7]);   // o=14
        sv[15] = fmaf(a, L3.w, sv[15]);  // o=15
    }

    // ---- recursive-halving butterfly over the 16 lanes of this query ----
    // stage m: low-half lanes keep slots [0,n/2), high keep [n/2,n); 15 shuffles
    {
        bool up = (lg & 1);
#pragma unroll
        for (int i = 0; i < 8; i++) {
            float keep = up ? sv[i + 8] : sv[i];
            float send = up ? sv[i] : sv[i + 8];
            sv[i] = keep + __shfl_xor(send, 1, 64);
        }
    }
    {
        bool up = (lg & 2);
#pragma unroll
        for (int i = 0; i < 4; i++) {
            float keep = up ? sv[i + 4] : sv[i];
            float send = up ? sv[i] : sv[i + 4];
            sv[i] = keep + __shfl_xor(send, 2, 64);
        }
    }
    {
        bool up = (lg & 4);
#pragma unroll
        for (int i = 0; i < 2; i++) {
            float keep = up ? sv[i + 2] : sv[i];
            float send = up ? sv[i] : sv[i + 2];
            sv[i] = keep + __shfl_xor(send, 4, 64);
        }
    }
    {
        bool up = (lg & 8);
        float keep = up ? sv[1] : sv[0];
        float send = up ? sv[0] : sv[1];
        sv[0] = keep + __shfl_xor(send, 8, 64);
    }
    // lane lg now holds observer lg's total (bitrev^2 = identity)

    const int qg = blockIdx.x * QPB + ql;
    out[qg * 16 + lg] = sv[0];
}

extern "C" void kernel_launch(void* const* d_in, const int* in_sizes, int n_in,
                              void* d_out, int out_size, void* d_ws, size_t ws_size,
                              hipStream_t stream) {
    const float* points = (const float*)d_in[0];
    const float* qc     = (const float*)d_in[1];
    const int*   sidx   = (const int*)d_in[2];
    // d_in[3] = mc_points: unused by the reference
    const float* cyp    = (const float*)d_in[4];
    const float* conep  = (const float*)d_in[5];
    const float* diskp  = (const float*)d_in[6];
    const float* ellp   = (const float*)d_in[7];
    const float* lam    = (const float*)d_in[8];
    float*       out    = (float*)d_out;

    const int totalQ = 2 * 8192;            // B*M = 16384
    dim3 grid(totalQ / QPB), block(256);    // 1024 blocks = 4/CU
    hipLaunchKernelGGL(gib_kernel, grid, block, 0, stream,
                       points, qc, sidx, cyp, conep, diskp, ellp, lam, out);
}

// Round 6
// 84.209 us; speedup vs baseline: 1.0416x; 1.0334x over previous
//
#include <hip/hip_runtime.h>

// GIB layer: B=2, N=65536, M=8192, K=32; 16 each of cy/cone/disk/ellip gibs;
// out = mean_k(gib_vals) @ lambdas -> (B, M, 16). fp32 in / fp32 out.
//
// R3-R5 post-mortem: three different structures all ~40us kernel, VALUBusy 22%,
// all pipes idle -> latency-bound; 2-4 waves/SIMD can't hide gather+LDS chains.
// R6: wave = 2 queries x 32 lanes, lane owns 2 gibs over all K=32.
//   - 8192 waves = 32 waves/CU (8/SIMD), __launch_bounds__(256,8)
//   - loads broadcast-coalesced (32 lanes same addr; 2 lines/wave-load)
//   - branchless unified arg forms; raw v_exp_f32/v_sqrt_f32 builtins
//   - no LDS in hot loop; one barrier (lambda staging, stride-18 = conflict-free)
//   - 16-shuffle halving butterfly w/ bit-reversed slots (verified in R5)

#define EPSF 1e-8f
#define LOG2E 1.4426950408889634f

constexpr int LAM_STRIDE = 18;  // floats; 18*dc % 32 == 0 only at dc=16 -> 2-way max (free)

__global__ __launch_bounds__(256, 8) void gib_kernel(
    const float* __restrict__ points,   // (B, 65536, 3)
    const float* __restrict__ qc,       // (B, 8192, 3)
    const int*   __restrict__ sidx,     // (B, 8192, 32)
    const float* __restrict__ cyp,      // (16,2)
    const float* __restrict__ conep,    // (16,2)
    const float* __restrict__ diskp,    // (16,2)
    const float* __restrict__ ellp,     // (16,3)
    const float* __restrict__ lam,      // (64,16)
    float*       __restrict__ out)      // (B, 8192, 16)
{
    __shared__ float lamS[64 * LAM_STRIDE];   // 4.6 KB, scaled by 1/K

    const int tid = threadIdx.x;

    // ---- stage lambda (64x16 -> stride-18 rows, scaled 1/32) ----
    {
        int g = tid >> 2, o = (tid & 3) * 4;
#pragma unroll
        for (int j = 0; j < 4; j++)
            lamS[g * LAM_STRIDE + o + j] = lam[g * 16 + o + j] * (1.0f / 32.0f);
    }
    __syncthreads();

    const int l  = tid & 63;
    const int c  = l & 31;               // gib column: a0 = row c, a1 = row 32+c
    const int qh = l >> 5;               // query half of wave
    const int q  = blockIdx.x * 8 + (tid >> 6) * 2 + qh;   // global query
    const int b  = q >> 13;

    // ---- per-lane branchless coefficients ----
    // a0 arg: u = al1*r2 + al2*s + al3*rz + al4 ; contrib = exp2(u*u*nb0)
    // a1 arg: v = rx2*A1 + ry2*B1 + rz2*C1     ; contrib = exp2(v)
    float al1, al2, al3, al4, nb0, A1, B1, C1;
    if (c < 16) {
        float c0 = cyp[2 * c], c1 = cyp[2 * c + 1];
        al1 = 1.f; al2 = 0.f; al3 = 0.f; al4 = -c0 * c0;
        nb0 = -LOG2E / (2.f * c1 * c1 + EPSF);
        float d0 = diskp[2 * c], d1 = diskp[2 * c + 1];
        float ai = -LOG2E / (d0 * d0 + EPSF);
        A1 = ai; B1 = ai; C1 = -LOG2E / (d1 * d1 + EPSF);
    } else {
        int cc = c - 16;
        float k0 = conep[2 * cc], k1 = conep[2 * cc + 1];
        al1 = 0.f; al2 = 1.f; al3 = -k0; al4 = 0.f;
        nb0 = -LOG2E / (2.f * k1 * k1 + EPSF);
        float e0 = ellp[3 * cc], e1 = ellp[3 * cc + 1], e2 = ellp[3 * cc + 2];
        A1 = -LOG2E / (e0 * e0 + EPSF);
        B1 = -LOG2E / (e1 * e1 + EPSF);
        C1 = -LOG2E / (e2 * e2 + EPSF);
    }

    const float* qq = qc + q * 3;
    const float qx = qq[0], qy = qq[1], qz = qq[2];
    const float* ptbase = points + (size_t)(b << 16) * 3;
    const int4*  idxp   = (const int4*)(sidx + q * 32);

    float a0 = 0.f, a1 = 0.f;
#pragma unroll
    for (int jc = 0; jc < 8; jc++) {
        const int4 i4 = idxp[jc];            // broadcast across the 32 lanes of q
        const int ii[4] = {i4.x, i4.y, i4.z, i4.w};
#pragma unroll
        for (int j = 0; j < 4; j++) {
            const float* pp = ptbase + ii[j] * 3;
            float rx = pp[0] - qx;
            float ry = pp[1] - qy;
            float rz = pp[2] - qz;
            float rx2 = rx * rx, ry2 = ry * ry, rz2 = rz * rz;
            float r2 = rx2 + ry2;
            float s  = __builtin_amdgcn_sqrtf(r2 + EPSF);
            float u  = fmaf(al1, r2, fmaf(al2, s, fmaf(al3, rz, al4)));
            a0 += __builtin_amdgcn_exp2f(u * u * nb0);
            float v  = fmaf(rx2, A1, fmaf(ry2, B1, rz2 * C1));
            a1 += __builtin_amdgcn_exp2f(v);
        }
    }

    // ---- lambda matvec into bit-reversed slots (slot brev4(o) <- observer o) ----
    float sv[16];
    {
        const float* ra = &lamS[c * LAM_STRIDE];
        const float* rb = &lamS[(32 + c) * LAM_STRIDE];
        // brev4 table: o -> slot
        // 0->0 1->8 2->4 3->12 4->2 5->10 6->6 7->14 8->1 9->9 10->5 11->13 12->3 13->11 14->7 15->15
#define GIB_MV(o, slot) { float2 La = *(const float2*)&ra[o]; float2 Lb = *(const float2*)&rb[o]; \
        sv[slot##0] = fmaf(a0, La.x, a1 * Lb.x); sv[slot##1] = fmaf(a0, La.y, a1 * Lb.y); }
        { float2 La = *(const float2*)&ra[0];  float2 Lb = *(const float2*)&rb[0];
          sv[0]  = fmaf(a0, La.x, a1 * Lb.x); sv[8]  = fmaf(a0, La.y, a1 * Lb.y); }
        { float2 La = *(const float2*)&ra[2];  float2 Lb = *(const float2*)&rb[2];
          sv[4]  = fmaf(a0, La.x, a1 * Lb.x); sv[12] = fmaf(a0, La.y, a1 * Lb.y); }
        { float2 La = *(const float2*)&ra[4];  float2 Lb = *(const float2*)&rb[4];
          sv[2]  = fmaf(a0, La.x, a1 * Lb.x); sv[10] = fmaf(a0, La.y, a1 * Lb.y); }
        { float2 La = *(const float2*)&ra[6];  float2 Lb = *(const float2*)&rb[6];
          sv[6]  = fmaf(a0, La.x, a1 * Lb.x); sv[14] = fmaf(a0, La.y, a1 * Lb.y); }
        { float2 La = *(const float2*)&ra[8];  float2 Lb = *(const float2*)&rb[8];
          sv[1]  = fmaf(a0, La.x, a1 * Lb.x); sv[9]  = fmaf(a0, La.y, a1 * Lb.y); }
        { float2 La = *(const float2*)&ra[10]; float2 Lb = *(const float2*)&rb[10];
          sv[5]  = fmaf(a0, La.x, a1 * Lb.x); sv[13] = fmaf(a0, La.y, a1 * Lb.y); }
        { float2 La = *(const float2*)&ra[12]; float2 Lb = *(const float2*)&rb[12];
          sv[3]  = fmaf(a0, La.x, a1 * Lb.x); sv[11] = fmaf(a0, La.y, a1 * Lb.y); }
        { float2 La = *(const float2*)&ra[14]; float2 Lb = *(const float2*)&rb[14];
          sv[7]  = fmaf(a0, La.x, a1 * Lb.x); sv[15] = fmaf(a0, La.y, a1 * Lb.y); }
#undef GIB_MV
    }

    // ---- recursive-halving butterfly over the 32 lanes of this query ----
    {
        bool up = (c & 1);
#pragma unroll
        for (int i = 0; i < 8; i++) {
            float keep = up ? sv[i + 8] : sv[i];
            float send = up ? sv[i] : sv[i + 8];
            sv[i] = keep + __shfl_xor(send, 1, 64);
        }
    }
    {
        bool up = (c & 2);
#pragma unroll
        for (int i = 0; i < 4; i++) {
            float keep = up ? sv[i + 4] : sv[i];
            float send = up ? sv[i] : sv[i + 4];
            sv[i] = keep + __shfl_xor(send, 2, 64);
        }
    }
    {
        bool up = (c & 4);
#pragma unroll
        for (int i = 0; i < 2; i++) {
            float keep = up ? sv[i + 2] : sv[i];
            float send = up ? sv[i] : sv[i + 2];
            sv[i] = keep + __shfl_xor(send, 4, 64);
        }
    }
    {
        bool up = (c & 8);
        float keep = up ? sv[1] : sv[0];
        float send = up ? sv[0] : sv[1];
        sv[0] = keep + __shfl_xor(send, 8, 64);
    }
    // merge the two 16-lane halves (c vs c+16): both hold observer (c&15) partials
    sv[0] += __shfl_xor(sv[0], 16, 64);

    if (c < 16)
        out[q * 16 + c] = sv[0];
}

extern "C" void kernel_launch(void* const* d_in, const int* in_sizes, int n_in,
                              void* d_out, int out_size, void* d_ws, size_t ws_size,
                              hipStream_t stream) {
    const float* points = (const float*)d_in[0];
    const float* qc     = (const float*)d_in[1];
    const int*   sidx   = (const int*)d_in[2];
    // d_in[3] = mc_points: unused by the reference
    const float* cyp    = (const float*)d_in[4];
    const float* conep  = (const float*)d_in[5];
    const float* diskp  = (const float*)d_in[6];
    const float* ellp   = (const float*)d_in[7];
    const float* lam    = (const float*)d_in[8];
    float*       out    = (float*)d_out;

    const int totalQ = 2 * 8192;            // B*M = 16384, 8 queries/block
    dim3 grid(totalQ / 8), block(256);      // 2048 blocks = 8/CU = 32 waves/CU
    hipLaunchKernelGGL(gib_kernel, grid, block, 0, stream,
                       points, qc, sidx, cyp, conep, diskp, ellp, lam, out);
}